// Round 7
// baseline (130.884 us; speedup 1.0000x reference)
//
#include <hip/hip_runtime.h>
#include <hip/hip_bf16.h>
#include <stdint.h>

// Fused causal attention head, MI355X (gfx950). Round 7.
// attn: barrier-free k-loop. Wave = 64 q-rows x 64-key tiles, self-staged
// K/V in private LDS (XOR-chunk swizzle, conflict-free), split-K=8 across
// the block's 4 waves x 2 block-halves (sh). In-LDS 4-wave combine (1
// barrier), 2 global partials -> combine kernel (R6-style).
// proj: R5 structure + register prefetch of phase-1 (hide global latency).

#define EMBED 384
#define HEAD  64
#define NB    4
#define NT    4096
#define NROWS (NB * NT) // 16384

#define SCALE_Q 0.18033688011112042f // 0.125 * log2(e), folded into Q

typedef short bf16x8 __attribute__((ext_vector_type(8)));
typedef float f32x4  __attribute__((ext_vector_type(4)));

__device__ __forceinline__ unsigned short bfround(float f) {
    union { float f; unsigned u; } v; v.f = f;
    return (unsigned short)((v.u + 0x8000u) >> 16);
}
__device__ __forceinline__ unsigned packbf(float lo, float hi) {
    union { float f; unsigned u; } a, b; a.f = lo; b.f = hi;
    return ((a.u + 0x8000u) >> 16) | ((b.u + 0x8000u) & 0xFFFF0000u);
}

// ---------------------------------------------------------------------------
__global__ __launch_bounds__(256)
void wprep_kernel(const float* __restrict__ Wq,
                  const float* __restrict__ Wk,
                  const float* __restrict__ Wv,
                  unsigned short* __restrict__ Wt)
{
    int idx = blockIdx.x * 256 + threadIdx.x;
    int k = idx / 192;
    int n = idx - k * 192;
    int sel = n >> 6, nc = n & 63;
    const float* wp = (sel == 0) ? Wq : ((sel == 1) ? Wk : Wv);
    Wt[n * EMBED + k] = bfround(wp[(size_t)k * HEAD + nc]);
}

// ---------------------------------------------------------------------------
// proj: 512 blocks = 256 row-groups x 2 col-halves; 64 rows x 96 cols.
// 2 K-phases; phase-1 W/x prefetched into regs during phase-0 compute.
// ---------------------------------------------------------------------------
__global__ __launch_bounds__(256)
void proj_kernel(const float* __restrict__ x,
                 const unsigned short* __restrict__ Wt,
                 unsigned short* __restrict__ Qo,
                 unsigned short* __restrict__ Ko,
                 unsigned short* __restrict__ Vto)
{
    __shared__ __attribute__((aligned(16))) unsigned short wsm[96][200];
    __shared__ __attribute__((aligned(16))) unsigned short xs[64][200];
    unsigned short (*vbuf)[72] = (unsigned short (*)[72])&xs[0][0];

    const int t    = threadIdx.x;
    const int w    = t >> 6;
    const int lane = t & 63;
    const int quad = lane >> 4;
    const int l16  = lane & 15;
    const int half = blockIdx.x & 1;
    const int r0   = (blockIdx.x >> 1) * 64;
    const int colbase = half * 96;

    f32x4 acc[6];
#pragma unroll
    for (int i = 0; i < 6; ++i) acc[i] = (f32x4){0.f, 0.f, 0.f, 0.f};

    uint4 wr[9]; float4 xr[12];
    // phase-0 loads
#pragma unroll
    for (int i = 0; i < 9; ++i) {
        int idx = t + i * 256; int row = idx / 24, c = idx - row * 24;
        wr[i] = *(const uint4*)(Wt + (size_t)(colbase + row) * EMBED + c * 8);
    }
#pragma unroll
    for (int i = 0; i < 12; ++i) {
        int idx = t + i * 256; int row = idx / 48, c4 = idx - row * 48;
        xr[i] = *(const float4*)(x + (size_t)(r0 + row) * EMBED + c4 * 4);
    }
#pragma unroll
    for (int i = 0; i < 9; ++i) {
        int idx = t + i * 256; int row = idx / 24, c = idx - row * 24;
        *(uint4*)&wsm[row][c * 8] = wr[i];
    }
#pragma unroll
    for (int i = 0; i < 12; ++i) {
        int idx = t + i * 256; int row = idx / 48, c4 = idx - row * 48;
        uint2 pw; pw.x = packbf(xr[i].x, xr[i].y); pw.y = packbf(xr[i].z, xr[i].w);
        *(uint2*)&xs[row][c4 * 4] = pw;
    }
    __syncthreads();
    // phase-1 prefetch (hidden under phase-0 compute)
#pragma unroll
    for (int i = 0; i < 9; ++i) {
        int idx = t + i * 256; int row = idx / 24, c = idx - row * 24;
        wr[i] = *(const uint4*)(Wt + (size_t)(colbase + row) * EMBED + 192 + c * 8);
    }
#pragma unroll
    for (int i = 0; i < 12; ++i) {
        int idx = t + i * 256; int row = idx / 48, c4 = idx - row * 48;
        xr[i] = *(const float4*)(x + (size_t)(r0 + row) * EMBED + 192 + c4 * 4);
    }
    // phase-0 compute
#pragma unroll
    for (int step = 0; step < 6; ++step) {
        bf16x8 a = *(const bf16x8*)&xs[w * 16 + l16][step * 32 + quad * 8];
#pragma unroll
        for (int ng = 0; ng < 6; ++ng) {
            bf16x8 b = *(const bf16x8*)&wsm[ng * 16 + l16][step * 32 + quad * 8];
            acc[ng] = __builtin_amdgcn_mfma_f32_16x16x32_bf16(a, b, acc[ng], 0, 0, 0);
        }
    }
    __syncthreads();
#pragma unroll
    for (int i = 0; i < 9; ++i) {
        int idx = t + i * 256; int row = idx / 24, c = idx - row * 24;
        *(uint4*)&wsm[row][c * 8] = wr[i];
    }
#pragma unroll
    for (int i = 0; i < 12; ++i) {
        int idx = t + i * 256; int row = idx / 48, c4 = idx - row * 48;
        uint2 pw; pw.x = packbf(xr[i].x, xr[i].y); pw.y = packbf(xr[i].z, xr[i].w);
        *(uint2*)&xs[row][c4 * 4] = pw;
    }
    __syncthreads();
    // phase-1 compute
#pragma unroll
    for (int step = 0; step < 6; ++step) {
        bf16x8 a = *(const bf16x8*)&xs[w * 16 + l16][step * 32 + quad * 8];
#pragma unroll
        for (int ng = 0; ng < 6; ++ng) {
            bf16x8 b = *(const bf16x8*)&wsm[ng * 16 + l16][step * 32 + quad * 8];
            acc[ng] = __builtin_amdgcn_mfma_f32_16x16x32_bf16(a, b, acc[ng], 0, 0, 0);
        }
    }
    __syncthreads(); // xs becomes vbuf

#pragma unroll
    for (int ng = 0; ng < 6; ++ng) {
        int cg = colbase + ng * 16 + l16;
#pragma unroll
        for (int r = 0; r < 4; ++r) {
            int row = r0 + w * 16 + quad * 4 + r;
            float vv = acc[ng][r];
            if (cg < 64) {
                Qo[(size_t)row * HEAD + cg] = bfround(vv * SCALE_Q);
            } else if (cg < 128) {
                Ko[(size_t)row * HEAD + (cg - 64)] = bfround(vv);
            } else {
                vbuf[cg - 128][w * 16 + quad * 4 + r] = bfround(vv);
            }
        }
    }
    __syncthreads();
    if (half == 1) {
        const int batch = r0 >> 12;
        const int s0 = r0 & (NT - 1);
#pragma unroll
        for (int i = 0; i < 2; ++i) {
            int idx = t + i * 256;
            int d = idx >> 3, c = idx & 7;
            *(uint4*)(Vto + ((size_t)(batch * HEAD + d)) * NT + s0 + c * 8) =
                *(const uint4*)&vbuf[d][c * 8];
        }
    }
}

// ---------------------------------------------------------------------------
// attn: 512 blocks x 256 thr. u: sh=u>>8, v=u&255, batch=v&3, mi=v>>2,
// m = sh ? mi : 63-mi (LPT: co-resident pair (u,u+256) works m + 63-m).
// Wave w = split s = sh*4+w; tiles kt = s, s+8, ... <= m (diag in split m&7).
// Each wave: 64 q-rows (4 subtiles) x 64-key tiles, private LDS K/V region,
// XOR-chunk swizzle, NO barriers in the loop. After loop: o -> LDS, one
// barrier, 4-wave combine -> opart/lpart (2 halves, combine kernel).
// ---------------------------------------------------------------------------
__global__ __launch_bounds__(256, 2)
void attn_kernel(const unsigned short* __restrict__ Qi,
                 const unsigned short* __restrict__ Ki,
                 const unsigned short* __restrict__ Vti,
                 float* __restrict__ opart,
                 float* __restrict__ lpart)
{
    __shared__ __attribute__((aligned(16))) unsigned short stage[4][2][64][64]; // 64KB
    __shared__ __attribute__((aligned(16))) unsigned short Ps[4][16][72];       // 9KB
    __shared__ float prs[4][64];                                                // 1KB

    const int t    = threadIdx.x;
    const int w    = t >> 6;
    const int lane = t & 63;
    const int quad = lane >> 4;
    const int l16  = lane & 15;
    const int g    = lane >> 3;      // 0..7 staging row group
    const int c    = lane & 7;       // staging chunk
    const int scc  = c ^ g;          // swizzled chunk (row%8 == g always)
    const int sw   = l16 & 7;        // frag-read swizzle key

    const int u     = blockIdx.x;
    const int sh    = u >> 8;
    const int v     = u & 255;
    const int batch = v & 3;
    const int mi    = v >> 2;
    const int m     = sh ? mi : (63 - mi);
    const int s     = sh * 4 + w;
    const int ntiles = (m >= s) ? (((m - s) >> 3) + 1) : 0;
    const int q0 = m * 64;

    const unsigned short* Kbg = Ki  + (size_t)batch * NT * HEAD;
    const unsigned short* Vbg = Vti + (size_t)batch * HEAD * NT;

    unsigned short (*Kt)[64] = stage[w][0];
    unsigned short (*Vs)[64] = stage[w][1];

    // Q B-frags for 4 q-subtiles (one-time; Q carries 0.125*log2e)
    bf16x8 bq0[4], bq1[4];
#pragma unroll
    for (int qs = 0; qs < 4; ++qs) {
        const unsigned short* qp = Qi + (size_t)(batch * NT + q0 + qs * 16 + l16) * HEAD + quad * 8;
        bq0[qs] = *(const bf16x8*)(qp);
        bq1[qs] = *(const bf16x8*)(qp + 32);
    }

    f32x4 o[4][4];
#pragma unroll
    for (int a = 0; a < 4; ++a)
#pragma unroll
        for (int b = 0; b < 4; ++b) o[a][b] = (f32x4){0.f, 0.f, 0.f, 0.f};
    float rs[4] = {0.f, 0.f, 0.f, 0.f};

    if (ntiles > 0) {
        uint4 kreg[8];
        // prologue: stage K tile kt=s
#pragma unroll
        for (int i = 0; i < 8; ++i)
            kreg[i] = *(const uint4*)(Kbg + (size_t)(s * 64 + i * 8 + g) * HEAD + c * 8);
#pragma unroll
        for (int i = 0; i < 8; ++i)
            *(uint4*)&Kt[i * 8 + g][scc * 8] = kreg[i];

        for (int j = 0; j < ntiles; ++j) {
            const int kt = s + 8 * j;
            // V loads for this tile (consumed mid-loop; latency hidden)
            uint4 vreg[8];
#pragma unroll
            for (int i = 0; i < 8; ++i)
                vreg[i] = *(const uint4*)(Vbg + (size_t)(i * 8 + g) * NT + kt * 64 + c * 8);
            // K frags (tile staged previously)
            bf16x8 ak0[4], ak1[4];
#pragma unroll
            for (int ts = 0; ts < 4; ++ts) {
                ak0[ts] = *(const bf16x8*)&Kt[ts * 16 + l16][(quad ^ sw) * 8];
                ak1[ts] = *(const bf16x8*)&Kt[ts * 16 + l16][((4 + quad) ^ sw) * 8];
            }
            // prefetch next K tile into regs
            if (j + 1 < ntiles) {
#pragma unroll
                for (int i = 0; i < 8; ++i)
                    kreg[i] = *(const uint4*)(Kbg + (size_t)((kt + 8) * 64 + i * 8 + g) * HEAD + c * 8);
            }
            const bool diag = (kt == m);
            bf16x8 ap0[4], ap1[4];
#pragma unroll
            for (int qs = 0; qs < 4; ++qs) {
                f32x4 z[4];
#pragma unroll
                for (int ts = 0; ts < 4; ++ts) {
                    f32x4 zz = (f32x4){0.f, 0.f, 0.f, 0.f};
                    zz = __builtin_amdgcn_mfma_f32_16x16x32_bf16(ak0[ts], bq0[qs], zz, 0, 0, 0);
                    zz = __builtin_amdgcn_mfma_f32_16x16x32_bf16(ak1[ts], bq1[qs], zz, 0, 0, 0);
                    z[ts] = zz;
                }
#pragma unroll
                for (int ts = 0; ts < 4; ++ts) {
                    float p[4];
#pragma unroll
                    for (int r = 0; r < 4; ++r) {
                        float pv = __builtin_amdgcn_exp2f(z[ts][r]);
                        if (diag) {
                            int sl = ts * 16 + quad * 4 + r;
                            int ql = qs * 16 + l16;
                            pv = (sl > ql) ? 0.f : pv;
                        }
                        p[r] = pv;
                    }
                    rs[qs] += (p[0] + p[1]) + (p[2] + p[3]);
                    uint2 pw; pw.x = packbf(p[0], p[1]); pw.y = packbf(p[2], p[3]);
                    *(uint2*)&Ps[w][l16][ts * 16 + quad * 4] = pw;
                }
                ap0[qs] = *(const bf16x8*)&Ps[w][l16][quad * 8];
                ap1[qs] = *(const bf16x8*)&Ps[w][l16][32 + quad * 8];
                if (qs == 0) { // V -> LDS (vmcnt drains under qs=0 compute)
#pragma unroll
                    for (int i = 0; i < 8; ++i)
                        *(uint4*)&Vs[i * 8 + g][scc * 8] = vreg[i];
                }
            }
            // next K tile -> LDS (WAR on this tile's K reads, same-wave order)
            if (j + 1 < ntiles) {
#pragma unroll
                for (int i = 0; i < 8; ++i)
                    *(uint4*)&Kt[i * 8 + g][scc * 8] = kreg[i];
            }
            // V frags + PV
            bf16x8 av0[4], av1[4];
#pragma unroll
            for (int nd = 0; nd < 4; ++nd) {
                av0[nd] = *(const bf16x8*)&Vs[nd * 16 + l16][(quad ^ sw) * 8];
                av1[nd] = *(const bf16x8*)&Vs[nd * 16 + l16][((4 + quad) ^ sw) * 8];
            }
#pragma unroll
            for (int qs = 0; qs < 4; ++qs)
#pragma unroll
                for (int nd = 0; nd < 4; ++nd) {
                    o[qs][nd] = __builtin_amdgcn_mfma_f32_16x16x32_bf16(ap0[qs], av0[nd], o[qs][nd], 0, 0, 0);
                    o[qs][nd] = __builtin_amdgcn_mfma_f32_16x16x32_bf16(ap1[qs], av1[nd], o[qs][nd], 0, 0, 0);
                }
        }
    }

    // rs: reduce over quads -> lane holds sum for q = qs*16 + l16
#pragma unroll
    for (int qs = 0; qs < 4; ++qs) {
        float vsum = rs[qs];
        vsum += __shfl_xor(vsum, 16, 64);
        vsum += __shfl_xor(vsum, 32, 64);
        if (quad == 0) prs[w][qs * 16 + l16] = vsum;
    }
    // stash o (fp32) into this wave's staging region [64 q][64 d]
    float* ost = (float*)&stage[w][0][0][0];
#pragma unroll
    for (int qs = 0; qs < 4; ++qs)
#pragma unroll
        for (int nd = 0; nd < 4; ++nd)
#pragma unroll
            for (int r = 0; r < 4; ++r)
                ost[(qs * 16 + quad * 4 + r) * 64 + nd * 16 + l16] = o[qs][nd][r];
    __syncthreads();

    // 4-wave combine: thread t -> q = t>>2, d-quarter = (t&3)*16
    {
        int q = t >> 2, dq = (t & 3) * 16;
        f32x4 sum[4];
#pragma unroll
        for (int p4 = 0; p4 < 4; ++p4) sum[p4] = (f32x4){0.f, 0.f, 0.f, 0.f};
#pragma unroll
        for (int w2 = 0; w2 < 4; ++w2) {
            const float* osw = (const float*)&stage[w2][0][0][0];
#pragma unroll
            for (int p4 = 0; p4 < 4; ++p4)
                sum[p4] += *(const f32x4*)&osw[q * 64 + dq + p4 * 4];
        }
        float rsum = prs[0][q] + prs[1][q] + prs[2][q] + prs[3][q];
        float* ob = opart + ((size_t)sh * NROWS + batch * NT + q0 + q) * HEAD + dq;
#pragma unroll
        for (int p4 = 0; p4 < 4; ++p4)
            *(f32x4*)(ob + p4 * 4) = sum[p4];
        if ((t & 3) == 0)
            lpart[(size_t)sh * NROWS + batch * NT + q0 + q] = rsum;
    }
}

// ---------------------------------------------------------------------------
__global__ __launch_bounds__(256)
void combine_kernel(const float* __restrict__ opart,
                    const float* __restrict__ lpart,
                    float* __restrict__ out)
{
    int gid = blockIdx.x * 256 + threadIdx.x;
    int row = gid >> 4;
    int d4  = (gid & 15) * 4;
    f32x4 a = *(const f32x4*)(opart + (size_t)row * HEAD + d4);
    f32x4 b = *(const f32x4*)(opart + (size_t)NROWS * HEAD + (size_t)row * HEAD + d4);
    float inv = 1.0f / (lpart[row] + lpart[NROWS + row]);
    f32x4 res = (a + b);
    res[0] *= inv; res[1] *= inv; res[2] *= inv; res[3] *= inv;
    *(f32x4*)(out + (size_t)row * HEAD + d4) = res;
}

extern "C" void kernel_launch(void* const* d_in, const int* in_sizes, int n_in,
                              void* d_out, int out_size, void* d_ws, size_t ws_size,
                              hipStream_t stream)
{
    const float* x  = (const float*)d_in[0];
    const float* Wq = (const float*)d_in[1];
    const float* Wk = (const float*)d_in[2];
    const float* Wv = (const float*)d_in[3];
    float* out = (float*)d_out;

    unsigned short* Qw  = (unsigned short*)d_ws;
    unsigned short* Kw  = Qw + (size_t)NROWS * HEAD;
    unsigned short* Vtw = Kw + (size_t)NROWS * HEAD;
    unsigned short* Wtw = Vtw + (size_t)NROWS * HEAD;
    float* opart = (float*)(Wtw + (size_t)192 * EMBED);
    float* lpart = opart + (size_t)2 * NROWS * HEAD;

    wprep_kernel<<<(192 * EMBED) / 256, 256, 0, stream>>>(Wq, Wk, Wv, Wtw);
    proj_kernel<<<512, 256, 0, stream>>>(x, Wtw, Qw, Kw, Vtw);
    attn_kernel<<<512, 256, 0, stream>>>(Qw, Kw, Vtw, opart, lpart);
    combine_kernel<<<NROWS * 16 / 256, 256, 0, stream>>>(opart, lpart, out);
}